// Round 12
// baseline (82.031 us; speedup 1.0000x reference)
//
#include <hip/hip_runtime.h>
#include <hip/hip_bf16.h>
#include <hip/hip_cooperative_groups.h>
#include <math.h>

namespace cg = cooperative_groups;

#define DD 128
#define HH 64
#define TT 12

typedef __bf16 bf16x8 __attribute__((ext_vector_type(8)));
typedef float  f32x4  __attribute__((ext_vector_type(4)));

__device__ __forceinline__ float fast_tanh(float x) {
    float ex = __expf(2.f * x);
    return (ex - 1.f) * __builtin_amdgcn_rcpf(ex + 1.f);
}

// Single cooperative kernel: 256 blocks x 1024 threads (1 block/CU).
// Phase 0: setup (segs/W3f/W4f/pads, grid-distributed) + W1->LDS frags +
//          dense scores (16 rows/wave, 16 waves/block) -> uexp, ytab.
// grid.sync()
// Phase 1: pooling (32-molecule tile/block, 1 seg per wave-half-iteration,
//          16-deep row-load pipeline) -> psh (LDS, reusing W1 buffer)
// Phase 2: predictor (waves 0-1, MFMA x2 layers) -> out.
// B-frag layout: elem(lane l, e) = W[32kk + 8*(l>>4) + e][16g + (l&15)]
__global__ __launch_bounds__(1024, 4) void kFused(
    const int* __restrict__ bidx, int* __restrict__ segs,
    const float* __restrict__ W1, const float* __restrict__ W3,
    __bf16* __restrict__ W3f, const float* __restrict__ W4,
    __bf16* __restrict__ W4f, const float* __restrict__ feat,
    const float* __restrict__ b1, const float* __restrict__ W2,
    const float* __restrict__ b2, float* __restrict__ uexp,
    __bf16* __restrict__ ytab, const int* __restrict__ fidx,
    const float* __restrict__ b3, const float* __restrict__ b4,
    float* __restrict__ out, int M, int B, int N)
{
    __shared__ __bf16 sW1f[16 * 512];   // 16 KB; reused as psh/hsh in phase 1/2
    int tid = threadIdx.x;
    int bId = blockIdx.x;
    int wave = tid >> 6, l = tid & 63;

    // ---- phase 0a: W1 frags -> LDS (all 1024 threads)
    for (int p = tid; p < HH * DD; p += 1024) {
        int d = p >> 6, j = p & 63;
        int f = (d >> 5) * 4 + (j >> 4);
        int lf = (((d >> 3) & 3) << 4) | (j & 15);
        sW1f[f * 512 + lf * 8 + (d & 7)] = (__bf16)W1[p];
    }
    // ---- phase 0b: grid-distributed setup
    int gt = bId * 1024 + tid;          // 0 .. 262143
#pragma unroll
    for (int k = 0; k < 2; ++k) {
        int m = gt + k * 262144;
        if (m < M) {
            int cur = bidx[m];
            int prev = (m == 0) ? -1 : bidx[m - 1];
            for (int b = prev + 1; b <= cur; ++b) segs[b] = m;
            if (m == M - 1)
                for (int b = cur + 1; b <= B; ++b) segs[b] = M;
        }
    }
    if (gt < DD * DD) {                  // W3f pack (coalesced source read)
        int d = gt >> 7, j = gt & 127;
        int f = (d >> 5) * 8 + (j >> 4);
        int lf = (((d >> 3) & 3) << 4) | (j & 15);
        W3f[f * 512 + lf * 8 + (d & 7)] = (__bf16)W3[gt];
    } else if (gt < DD * DD + 4 * 512) { // W4f pack (padded 128x16, cols 12-15 = 0)
        int p = gt - DD * DD;
        int f = p >> 9, lf = (p >> 3) & 63, e = p & 7;
        int d = 32 * f + 8 * (lf >> 4) + e;
        int c = lf & 15;
        W4f[p] = (c < TT) ? (__bf16)W4[d * TT + c] : (__bf16)0.f;
    } else if (gt < DD * DD + 4 * 512 + 16) {  // zero row of ytab
        reinterpret_cast<uint4*>(ytab + (size_t)N * DD)[gt - (DD * DD + 4 * 512)] =
            make_uint4(0u, 0u, 0u, 0u);
    } else if (gt == DD * DD + 4 * 512 + 16) {
        uexp[N] = 0.f;
    }
    __syncthreads();

    // ---- phase 0c: dense scores, 16 rows per wave
    int m0 = (bId * 16 + wave) * 16;
    int r = l & 15, grp = l >> 4;
    if (m0 < N) {
        int row = min(m0 + r, N - 1);
        const float* xr = feat + (size_t)row * DD + grp * 8;
        bf16x8 a[4];
#pragma unroll
        for (int kk = 0; kk < 4; ++kk) {
            float4 u = *reinterpret_cast<const float4*>(xr + kk * 32);
            float4 v = *reinterpret_cast<const float4*>(xr + kk * 32 + 4);
            bf16x8 t;
            t[0] = (__bf16)u.x; t[1] = (__bf16)u.y; t[2] = (__bf16)u.z; t[3] = (__bf16)u.w;
            t[4] = (__bf16)v.x; t[5] = (__bf16)v.y; t[6] = (__bf16)v.z; t[7] = (__bf16)v.w;
            a[kk] = t;
        }
        f32x4 acc[4] = {};
#pragma unroll
        for (int kk = 0; kk < 4; ++kk) {
#pragma unroll
            for (int g = 0; g < 4; ++g) {
                bf16x8 bfr = *reinterpret_cast<const bf16x8*>(sW1f + (kk * 4 + g) * 512 + l * 8);
                acc[g] = __builtin_amdgcn_mfma_f32_16x16x32_bf16(a[kk], bfr, acc[g], 0, 0, 0);
            }
        }
        float part[4] = {0.f, 0.f, 0.f, 0.f};
#pragma unroll
        for (int g = 0; g < 4; ++g) {
            int j = 16 * g + r;
            float b1j = b1[j], w2j = W2[j];
#pragma unroll
            for (int q = 0; q < 4; ++q)
                part[q] = fmaf(fast_tanh(acc[g][q] + b1j), w2j, part[q]);
        }
#pragma unroll
        for (int q = 0; q < 4; ++q) {
#pragma unroll
            for (int off = 1; off < 16; off <<= 1)
                part[q] += __shfl_xor(part[q], off, 64);
        }
        // transpose: score[m0+r] lives at lane 16*(r>>2)+r, component r&3
        float v01 = (r & 1) ? part[1] : part[0];
        float v23 = (r & 1) ? part[3] : part[2];
        float vsel = (r & 2) ? v23 : v01;
        float sc = __shfl(vsel, ((r >> 2) << 4) | r, 64);
        float ue = __expf(sc + b2[0]);   // scores bounded; max-sub dropped
        if (grp == 0) uexp[m0 + r] = ue;
        __bf16* dst = ytab + (size_t)row * DD + grp * 8;
#pragma unroll
        for (int kk = 0; kk < 4; ++kk) {
            bf16x8 t;
#pragma unroll
            for (int e = 0; e < 8; ++e) t[e] = (__bf16)(ue * (float)a[kk][e]);
            *reinterpret_cast<bf16x8*>(dst + kk * 32) = t;
        }
    }

    cg::this_grid().sync();

    // ---- phase 1: pooling. LDS reuse: psh[32][DD] | hsh[32][DD]
    typedef __bf16 (*rowArr)[DD];
    rowArr psh = (rowArr)sW1f;
    rowArr hsh = (rowArr)(sW1f + 32 * DD);
    int sub = l >> 4, c16 = l & 15;
    const __bf16* yb = ytab + c16 * 8;

#pragma unroll
    for (int s = 0; s < 2; ++s) {
        int seg = bId * 32 + 2 * wave + s;
        int rowit = 2 * wave + s;
        float acc[8] = {0.f, 0.f, 0.f, 0.f, 0.f, 0.f, 0.f, 0.f};
        float denl = 0.f;
        if (seg < B) {
            int start = segs[seg], end = segs[seg + 1];
            for (int base = start; base < end; base += 64) {
                int idxs[16];
#pragma unroll
                for (int i = 0; i < 16; ++i) {
                    int p = base + 4 * i + sub;
                    int v = fidx[min(p, M - 1)];
                    idxs[i] = (p < end) ? v : N;           // N -> zero row
                }
                int t = base + l;
                int fi = (t < end) ? fidx[t] : N;
                denl += uexp[fi];                           // uexp[N] = 0
#pragma unroll
                for (int i = 0; i < 16; ++i) {
                    uint4 u4 = *reinterpret_cast<const uint4*>(yb + (size_t)idxs[i] * DD);
                    acc[0] += __builtin_bit_cast(float, u4.x << 16);
                    acc[1] += __builtin_bit_cast(float, u4.x & 0xffff0000u);
                    acc[2] += __builtin_bit_cast(float, u4.y << 16);
                    acc[3] += __builtin_bit_cast(float, u4.y & 0xffff0000u);
                    acc[4] += __builtin_bit_cast(float, u4.z << 16);
                    acc[5] += __builtin_bit_cast(float, u4.z & 0xffff0000u);
                    acc[6] += __builtin_bit_cast(float, u4.w << 16);
                    acc[7] += __builtin_bit_cast(float, u4.w & 0xffff0000u);
                }
            }
        }
        float den = denl;
#pragma unroll
        for (int off = 1; off < 64; off <<= 1) den += __shfl_xor(den, off, 64);
#pragma unroll
        for (int j = 0; j < 8; ++j) {
            acc[j] += __shfl_xor(acc[j], 16, 64);
            acc[j] += __shfl_xor(acc[j], 32, 64);
        }
        if (sub == 0) {
            float inv = 1.f / (den + 1e-16f);
            bf16x8 o;
#pragma unroll
            for (int j = 0; j < 8; ++j) o[j] = (__bf16)(acc[j] * inv);
            *reinterpret_cast<bf16x8*>(&psh[rowit][c16 * 8]) = o;
        }
    }
    __syncthreads();

    if (wave >= 2) return;
    // ---- phase 2: predictor (waves 0,1; 16 rows each)
    int rbase = wave * 16;
    bf16x8 a2[4];
#pragma unroll
    for (int kk = 0; kk < 4; ++kk)
        a2[kk] = *reinterpret_cast<const bf16x8*>(&psh[rbase + r][kk * 32 + grp * 8]);

    f32x4 acc1[8] = {};
#pragma unroll
    for (int kk = 0; kk < 4; ++kk) {
#pragma unroll
        for (int g = 0; g < 8; ++g) {
            bf16x8 bfr = *reinterpret_cast<const bf16x8*>(W3f + (kk * 8 + g) * 512 + l * 8);
            acc1[g] = __builtin_amdgcn_mfma_f32_16x16x32_bf16(a2[kk], bfr, acc1[g], 0, 0, 0);
        }
    }
#pragma unroll
    for (int g = 0; g < 8; ++g) {
        int j = 16 * g + r;
        float b3j = b3[j];
#pragma unroll
        for (int q = 0; q < 4; ++q)
            hsh[rbase + 4 * grp + q][j] = (__bf16)fmaxf(acc1[g][q] + b3j, 0.f);
    }
    f32x4 acc2 = {};
#pragma unroll
    for (int kk = 0; kk < 4; ++kk) {
        bf16x8 ah = *reinterpret_cast<const bf16x8*>(&hsh[rbase + r][kk * 32 + grp * 8]);
        bf16x8 bw = *reinterpret_cast<const bf16x8*>(W4f + kk * 512 + l * 8);
        acc2 = __builtin_amdgcn_mfma_f32_16x16x32_bf16(ah, bw, acc2, 0, 0, 0);
    }
    if (r < TT) {
        float b4t = b4[r];
#pragma unroll
        for (int q = 0; q < 4; ++q) {
            int ro = bId * 32 + rbase + 4 * grp + q;
            if (ro < B) out[(size_t)ro * TT + r] = acc2[q] + b4t;
        }
    }
}

extern "C" void kernel_launch(void* const* d_in, const int* in_sizes, int n_in,
                              void* d_out, int out_size, void* d_ws, size_t ws_size,
                              hipStream_t stream) {
    const int*   bidx = (const int*)d_in[2];
    const float* W1 = (const float*)d_in[4];
    const float* b1 = (const float*)d_in[5];
    const float* W2 = (const float*)d_in[6];
    const float* b2 = (const float*)d_in[7];
    const float* W3 = (const float*)d_in[8];
    const float* b3 = (const float*)d_in[9];
    const float* W4 = (const float*)d_in[10];
    const float* b4 = (const float*)d_in[11];
    const float* feat = (const float*)d_in[0];
    const int*   fidx = (const int*)d_in[1];

    int N = in_sizes[0] / DD;
    int M = in_sizes[1];
    int B = out_size / TT;
    float* out = (float*)d_out;

    char* ws = (char*)d_ws;
    size_t o = 0;
    auto alloc = [&](size_t bytes) -> char* {
        char* p = ws + o;
        o = (o + bytes + 255) & ~(size_t)255;
        return p;
    };
    float*  uexp = (float*)alloc((size_t)(N + 1) * 4);
    __bf16* W3f  = (__bf16*)alloc(32 * 512 * 2);
    __bf16* W4f  = (__bf16*)alloc(4 * 512 * 2);
    int*    segs = (int*)alloc((size_t)(B + 1) * 4);
    __bf16* ytab = (__bf16*)alloc((size_t)(N + 1) * DD * 2);

    void* args[] = {
        (void*)&bidx, (void*)&segs, (void*)&W1, (void*)&W3, (void*)&W3f,
        (void*)&W4, (void*)&W4f, (void*)&feat, (void*)&b1, (void*)&W2,
        (void*)&b2, (void*)&uexp, (void*)&ytab, (void*)&fidx,
        (void*)&b3, (void*)&b4, (void*)&out, (void*)&M, (void*)&B, (void*)&N
    };
    hipLaunchCooperativeKernel((const void*)kFused, dim3(256), dim3(1024),
                               args, 0, stream);
}

// Round 13
// 37.818 us; speedup vs baseline: 2.1691x; 2.1691x over previous
//
#include <hip/hip_runtime.h>
#include <hip/hip_bf16.h>
#include <math.h>

#define DD 128
#define HH 64
#define TT 12

typedef __bf16 bf16x8 __attribute__((ext_vector_type(8)));
typedef float  f32x4  __attribute__((ext_vector_type(4)));

__device__ __forceinline__ float fast_tanh(float x) {
    float ex = __expf(2.f * x);
    return (ex - 1.f) * __builtin_amdgcn_rcpf(ex + 1.f);
}

// ---------------- K1: fused dense scores (blocks 0..nScore-1, dispatched
// FIRST — they are the long pole) + setup (segs/W3f/W4f/pads, blocks after).
// Score: W1 frags in LDS, 32 rows/wave (2 tiles), uexp[n]=exp(score+b2),
// weighted bf16 table y[n] = uexp[n]*x[n].
// B-frag layout: elem(lane l, e) = W[32kk + 8*(l>>4) + e][16g + (l&15)]
__global__ __launch_bounds__(256) void kMain(
    const int* __restrict__ bidx, int* __restrict__ segs,
    const float* __restrict__ W1, const float* __restrict__ W3,
    __bf16* __restrict__ W3f, const float* __restrict__ W4,
    __bf16* __restrict__ W4f, const float* __restrict__ feat,
    const float* __restrict__ b1, const float* __restrict__ W2,
    const float* __restrict__ b2, float* __restrict__ uexp,
    __bf16* __restrict__ ytab, int M, int B, int N, int nScore)
{
    __shared__ __bf16 sW1f[16 * 512];
    int tid = threadIdx.x;
    if ((int)blockIdx.x >= nScore) {
        // ---- setup path
        int sb = blockIdx.x - nScore;
        int m = sb * 256 + tid;
        if (m < DD * DD) {  // W3f pack, source-major (coalesced read)
            int d = m >> 7, j = m & 127;
            int f = (d >> 5) * 8 + (j >> 4);
            int l = (((d >> 3) & 3) << 4) | (j & 15);
            W3f[f * 512 + l * 8 + (d & 7)] = (__bf16)W3[m];
        }
        if (sb == 0) {
            // W4f: padded 128x16 B-frags (cols 12..15 = 0)
            for (int p = tid; p < 4 * 512; p += 256) {
                int f = p >> 9, l = (p >> 3) & 63, e = p & 7;
                int d = 32 * f + 8 * (l >> 4) + e;
                int c = l & 15;
                W4f[p] = (c < TT) ? (__bf16)W4[d * TT + c] : (__bf16)0.f;
            }
            if (tid >= 64 && tid < 128)
                reinterpret_cast<unsigned*>(ytab + (size_t)N * DD)[tid - 64] = 0u;
            if (tid == 0) uexp[N] = 0.f;
        }
        if (m < M) {
            int cur = bidx[m];
            int prev = (m == 0) ? -1 : bidx[m - 1];
            for (int b = prev + 1; b <= cur; ++b) segs[b] = m;
            if (m == M - 1)
                for (int b = cur + 1; b <= B; ++b) segs[b] = M;
        }
        return;
    }
    // ---- score path: 128 rows/block, 32/wave
    for (int p = tid; p < HH * DD; p += 256) {
        int d = p >> 6, j = p & 63;
        int f = (d >> 5) * 4 + (j >> 4);
        int l = (((d >> 3) & 3) << 4) | (j & 15);
        sW1f[f * 512 + l * 8 + (d & 7)] = (__bf16)W1[p];
    }
    __syncthreads();
    int wave = tid >> 6, l = tid & 63;
    int m0 = (blockIdx.x * 4 + wave) * 32;
    if (m0 >= N) return;
    int r = l & 15, grp = l >> 4;

    bf16x8 a[2][4];
#pragma unroll
    for (int hf = 0; hf < 2; ++hf) {
        int row = min(m0 + hf * 16 + r, N - 1);
        const float* xr = feat + (size_t)row * DD + grp * 8;
#pragma unroll
        for (int kk = 0; kk < 4; ++kk) {
            float4 u = *reinterpret_cast<const float4*>(xr + kk * 32);
            float4 v = *reinterpret_cast<const float4*>(xr + kk * 32 + 4);
            bf16x8 t;
            t[0] = (__bf16)u.x; t[1] = (__bf16)u.y; t[2] = (__bf16)u.z; t[3] = (__bf16)u.w;
            t[4] = (__bf16)v.x; t[5] = (__bf16)v.y; t[6] = (__bf16)v.z; t[7] = (__bf16)v.w;
            a[hf][kk] = t;
        }
    }

    f32x4 acc[2][4] = {};
#pragma unroll
    for (int kk = 0; kk < 4; ++kk) {
#pragma unroll
        for (int g = 0; g < 4; ++g) {
            bf16x8 bfr = *reinterpret_cast<const bf16x8*>(sW1f + (kk * 4 + g) * 512 + l * 8);
            acc[0][g] = __builtin_amdgcn_mfma_f32_16x16x32_bf16(a[0][kk], bfr, acc[0][g], 0, 0, 0);
            acc[1][g] = __builtin_amdgcn_mfma_f32_16x16x32_bf16(a[1][kk], bfr, acc[1][g], 0, 0, 0);
        }
    }

    float b2v = b2[0];
#pragma unroll
    for (int hf = 0; hf < 2; ++hf) {
        float part[4] = {0.f, 0.f, 0.f, 0.f};
#pragma unroll
        for (int g = 0; g < 4; ++g) {
            int j = 16 * g + r;
            float b1j = b1[j], w2j = W2[j];
#pragma unroll
            for (int q = 0; q < 4; ++q)
                part[q] = fmaf(fast_tanh(acc[hf][g][q] + b1j), w2j, part[q]);
        }
#pragma unroll
        for (int q = 0; q < 4; ++q) {
#pragma unroll
            for (int off = 1; off < 16; off <<= 1)
                part[q] += __shfl_xor(part[q], off, 64);
        }
        // transpose: score[mh+r] lives at lane 16*(r>>2)+r, component r&3
        float v01 = (r & 1) ? part[1] : part[0];
        float v23 = (r & 1) ? part[3] : part[2];
        float vsel = (r & 2) ? v23 : v01;
        float sc = __shfl(vsel, ((r >> 2) << 4) | r, 64);
        float ue = __expf(sc + b2v);      // scores bounded; max-sub dropped
        int mh = m0 + hf * 16;
        if (grp == 0) uexp[mh + r] = ue;
        int row = min(mh + r, N - 1);
        __bf16* dst = ytab + (size_t)row * DD + grp * 8;
#pragma unroll
        for (int kk = 0; kk < 4; ++kk) {
            bf16x8 t;
#pragma unroll
            for (int e = 0; e < 8; ++e) t[e] = (__bf16)(ue * (float)a[hf][kk][e]);
            *reinterpret_cast<bf16x8*>(dst + kk * 32) = t;
        }
    }
}

// ---------------- K2: fused pooling + predictor — r9/r11-proven structure.
// One block per 16-molecule tile, 8 waves x 2 segments; NO min-wave bound
// (r10/r12 lesson: any VGPR cap spills/serializes the 16-deep load pipeline).
__global__ __launch_bounds__(512) void kPoolPred(
    const __bf16* __restrict__ ytab, const int* __restrict__ fidx,
    const float* __restrict__ uexp, const int* __restrict__ segs,
    const __bf16* __restrict__ W3f, const __bf16* __restrict__ W4f,
    const float* __restrict__ b3, const float* __restrict__ b4,
    float* __restrict__ out, int B, int NZ, int M)
{
    __shared__ __bf16 psh[16][DD];   // pooled tile, bf16
    __shared__ __bf16 hsh[16][DD];   // relu hidden, bf16
    int tid = threadIdx.x;
    int w = tid >> 6, lane = tid & 63;
    int tile = blockIdx.x;
    int sub = lane >> 4, c16 = lane & 15;
    const __bf16* yb = ytab + c16 * 8;

#pragma unroll
    for (int s = 0; s < 2; ++s) {
        int seg = tile * 16 + 2 * w + s;
        int rowit = 2 * w + s;
        float acc[8] = {0.f, 0.f, 0.f, 0.f, 0.f, 0.f, 0.f, 0.f};
        float denl = 0.f;
        if (seg < B) {
            int start = segs[seg], end = segs[seg + 1];
            for (int base = start; base < end; base += 64) {
                int idxs[16];
#pragma unroll
                for (int i = 0; i < 16; ++i) {
                    int p = base + 4 * i + sub;
                    int v = fidx[min(p, M - 1)];
                    idxs[i] = (p < end) ? v : NZ;          // NZ -> zero row
                }
                int t = base + lane;
                int fi = (t < end) ? fidx[t] : NZ;
                denl += uexp[fi];                           // uexp[NZ] = 0
#pragma unroll
                for (int i = 0; i < 16; ++i) {
                    uint4 u4 = *reinterpret_cast<const uint4*>(yb + (size_t)idxs[i] * DD);
                    acc[0] += __builtin_bit_cast(float, u4.x << 16);
                    acc[1] += __builtin_bit_cast(float, u4.x & 0xffff0000u);
                    acc[2] += __builtin_bit_cast(float, u4.y << 16);
                    acc[3] += __builtin_bit_cast(float, u4.y & 0xffff0000u);
                    acc[4] += __builtin_bit_cast(float, u4.z << 16);
                    acc[5] += __builtin_bit_cast(float, u4.z & 0xffff0000u);
                    acc[6] += __builtin_bit_cast(float, u4.w << 16);
                    acc[7] += __builtin_bit_cast(float, u4.w & 0xffff0000u);
                }
            }
        }
        float den = denl;
#pragma unroll
        for (int off = 1; off < 64; off <<= 1) den += __shfl_xor(den, off, 64);
#pragma unroll
        for (int j = 0; j < 8; ++j) {
            acc[j] += __shfl_xor(acc[j], 16, 64);
            acc[j] += __shfl_xor(acc[j], 32, 64);
        }
        if (sub == 0) {
            float inv = 1.f / (den + 1e-16f);
            bf16x8 o;
#pragma unroll
            for (int j = 0; j < 8; ++j) o[j] = (__bf16)(acc[j] * inv);
            *reinterpret_cast<bf16x8*>(&psh[rowit][c16 * 8]) = o;
        }
    }
    __syncthreads();

    if (w != 0) return;
    // ---- pred (wave 0): logits = relu(P@W3+b3)@W4 + b4
    int r = lane & 15, grp = lane >> 4;
    bf16x8 a[4];
#pragma unroll
    for (int kk = 0; kk < 4; ++kk)
        a[kk] = *reinterpret_cast<const bf16x8*>(&psh[r][kk * 32 + grp * 8]);

    f32x4 acc1[8] = {};
#pragma unroll
    for (int kk = 0; kk < 4; ++kk) {
#pragma unroll
        for (int g = 0; g < 8; ++g) {
            bf16x8 bfr = *reinterpret_cast<const bf16x8*>(W3f + (kk * 8 + g) * 512 + lane * 8);
            acc1[g] = __builtin_amdgcn_mfma_f32_16x16x32_bf16(a[kk], bfr, acc1[g], 0, 0, 0);
        }
    }
#pragma unroll
    for (int g = 0; g < 8; ++g) {
        int j = 16 * g + r;
        float b3j = b3[j];
#pragma unroll
        for (int q = 0; q < 4; ++q)
            hsh[4 * grp + q][j] = (__bf16)fmaxf(acc1[g][q] + b3j, 0.f);
    }
    f32x4 acc2 = {};
#pragma unroll
    for (int kk = 0; kk < 4; ++kk) {
        bf16x8 ah = *reinterpret_cast<const bf16x8*>(&hsh[r][kk * 32 + grp * 8]);
        bf16x8 bw = *reinterpret_cast<const bf16x8*>(W4f + kk * 512 + lane * 8);
        acc2 = __builtin_amdgcn_mfma_f32_16x16x32_bf16(ah, bw, acc2, 0, 0, 0);
    }
    if (r < TT) {
        float b4t = b4[r];
#pragma unroll
        for (int q = 0; q < 4; ++q) {
            int ro = tile * 16 + 4 * grp + q;
            if (ro < B) out[(size_t)ro * TT + r] = acc2[q] + b4t;
        }
    }
}

extern "C" void kernel_launch(void* const* d_in, const int* in_sizes, int n_in,
                              void* d_out, int out_size, void* d_ws, size_t ws_size,
                              hipStream_t stream) {
    const float* feat = (const float*)d_in[0];
    const int*   fidx = (const int*)d_in[1];
    const int*   bidx = (const int*)d_in[2];
    const float* W1 = (const float*)d_in[4];
    const float* b1 = (const float*)d_in[5];
    const float* W2 = (const float*)d_in[6];
    const float* b2 = (const float*)d_in[7];
    const float* W3 = (const float*)d_in[8];
    const float* b3 = (const float*)d_in[9];
    const float* W4 = (const float*)d_in[10];
    const float* b4 = (const float*)d_in[11];

    int N = in_sizes[0] / DD;
    int M = in_sizes[1];
    int B = out_size / TT;
    float* out = (float*)d_out;

    char* ws = (char*)d_ws;
    size_t o = 0;
    auto alloc = [&](size_t bytes) -> char* {
        char* p = ws + o;
        o = (o + bytes + 255) & ~(size_t)255;
        return p;
    };
    float*  uexp = (float*)alloc((size_t)(N + 1) * 4);
    __bf16* W3f  = (__bf16*)alloc(32 * 512 * 2);
    __bf16* W4f  = (__bf16*)alloc(4 * 512 * 2);
    int*    segs = (int*)alloc((size_t)(B + 1) * 4);
    __bf16* ytab = (__bf16*)alloc((size_t)(N + 1) * DD * 2);

    int nScore = (N + 127) / 128;
    int nSetup = (M + 255) / 256;
    kMain<<<nScore + nSetup, 256, 0, stream>>>(bidx, segs, W1, W3, W3f, W4, W4f,
                                               feat, b1, W2, b2, uexp, ytab,
                                               M, B, N, nScore);
    int ntiles = (B + 15) / 16;
    kPoolPred<<<ntiles, 512, 0, stream>>>(ytab, fidx, uexp, segs, W3f, W4f,
                                          b3, b4, out, B, N, M);
}